// Round 1
// baseline (2472.807 us; speedup 1.0000x reference)
//
#include <hip/hip_runtime.h>

#define RD 256
#define BT 32   // batch tile per block

__device__ __forceinline__ float fast_tanh(float x) {
  // tanh(x) = 1 - 2/(exp(2x)+1); saturates correctly for |x| large
  float e = __expf(2.0f * x);
  return 1.0f - 2.0f / (e + 1.0f);
}

// Pre-transpose B1 (256x256) and B2 (8x256x256) into Wt[9][k][r] so the main
// kernel's W loads are coalesced float4 along r.
__global__ __launch_bounds__(256) void transpose_w(
    const float* __restrict__ B1, const float* __restrict__ B2,
    float* __restrict__ Wt) {
  const int w = blockIdx.z, bi = blockIdx.y, bj = blockIdx.x;
  __shared__ float tile[32][33];
  const int c = threadIdx.x & 31, r4 = (threadIdx.x >> 5) << 2;
  const float* src = (w == 0) ? B1 : (B2 + (size_t)(w - 1) * RD * RD);
  #pragma unroll
  for (int i = 0; i < 4; ++i)
    tile[r4 + i][c] = src[(size_t)(bi * 32 + r4 + i) * RD + bj * 32 + c];
  __syncthreads();
  #pragma unroll
  for (int i = 0; i < 4; ++i)
    Wt[((size_t)w * RD + bj * 32 + r4 + i) * RD + bi * 32 + c] = tile[c][r4 + i];
}

__global__ __launch_bounds__(256) void sde_main(
    const float* __restrict__ V, const float* __restrict__ inc,
    const float* __restrict__ W1, const float* __restrict__ b1,
    const float* __restrict__ W2, const float* __restrict__ b2,
    const float* __restrict__ rho1p, const float* __restrict__ rho2p,
    const float* __restrict__ rho3p, const float* __restrict__ rho4p,
    const float* __restrict__ lam1, const float* __restrict__ lam2,
    const float* __restrict__ Wro, const float* __restrict__ bro,
    const float* __restrict__ Wt, float* __restrict__ out) {
  __shared__ float R_T[RD][BT];      // state, k-major, batch-minor (32 KB)
  __shared__ float actT[32][33];     // hidden activations (prologue only)
  __shared__ float dW[9][BT][8];     // Brownian increments per step
  __shared__ float ro_part[8][BT];   // readout partials

  const int tid = threadIdx.x;
  const int b_base = blockIdx.x * BT;
  const float rho1 = rho1p[0], rho2 = rho2p[0], rho3 = rho3p[0], rho4 = rho4p[0];

  // ---- prologue: act = tanh(V @ W1^T + b1), stored actT[h][b] ----
  {
    const int b = tid & 31, h0 = (tid >> 5) << 2;
    const float* Vb = V + (size_t)(b_base + b) * 16;
    float v[16];
    #pragma unroll
    for (int k = 0; k < 16; ++k) v[k] = Vb[k];
    #pragma unroll
    for (int i = 0; i < 4; ++i) {
      const int h = h0 + i;
      float s = b1[h];
      #pragma unroll
      for (int k = 0; k < 16; ++k) s += v[k] * W1[h * 16 + k];
      actT[h][b] = fast_tanh(s);
    }
  }
  // ---- prologue: dW[t][b][m].  dW[0]=inc[0]+inc[1]; dW[t]=inc[t+1] ----
  {
    const int b = tid >> 3, m = tid & 7;
    const float* ib = inc + (size_t)(b_base + b) * 80 + m;
    dW[0][b][m] = ib[0] + ib[8];
    #pragma unroll
    for (int t = 1; t < 9; ++t) dW[t][b][m] = ib[(t + 1) * 8];
  }
  __syncthreads();

  const int g = tid & 63;        // row group: rows r0..r0+3
  const int r0 = g << 2;
  const int b0 = (tid >> 6) << 3; // batch group: batches b0..b0+7

  // ---- R0 = act @ W2^T + b2, written into R_T ----
  {
    float y[4][8];
    #pragma unroll
    for (int i = 0; i < 4; ++i)
      #pragma unroll
      for (int j = 0; j < 8; ++j) y[i][j] = 0.f;
    #pragma unroll 4
    for (int h = 0; h < 32; ++h) {
      float a[8];
      #pragma unroll
      for (int j = 0; j < 8; ++j) a[j] = actT[h][b0 + j];
      float wv[4];
      #pragma unroll
      for (int i = 0; i < 4; ++i) wv[i] = W2[(size_t)(r0 + i) * 32 + h];
      #pragma unroll
      for (int i = 0; i < 4; ++i)
        #pragma unroll
        for (int j = 0; j < 8; ++j) y[i][j] += wv[i] * a[j];
    }
    #pragma unroll
    for (int i = 0; i < 4; ++i) {
      const float bb = b2[r0 + i];
      #pragma unroll
      for (int j = 0; j < 8; ++j) R_T[r0 + i][b0 + j] = y[i][j] + bb;
    }
  }
  __syncthreads();

  // ---- readout for timestep t (R_T currently holds R_t) ----
  auto readout = [&](int t) {
    const int b = tid & 31, c = tid >> 5;
    const float* wr = Wro + (size_t)t * RD + c * 32;
    float s = 0.f;
    #pragma unroll 8
    for (int rr = 0; rr < 32; ++rr) s += R_T[c * 32 + rr][b] * wr[rr];
    ro_part[c][b] = s;
    __syncthreads();
    if (tid < 32) {
      float x = bro[t];
      #pragma unroll
      for (int cc = 0; cc < 8; ++cc) x += ro_part[cc][tid];
      out[(size_t)(b_base + tid) * 10 + t] = x;
    }
    __syncthreads();
  };

  readout(0);

  // ---- main recurrence: 9 steps, 9 matvecs each ----
  for (int t = 0; t < 9; ++t) {
    float Racc[4][8];
    #pragma unroll
    for (int i = 0; i < 4; ++i)
      #pragma unroll
      for (int j = 0; j < 8; ++j) Racc[i][j] = R_T[r0 + i][b0 + j];

    #pragma unroll 1
    for (int w = 0; w < 9; ++w) {
      float Y[4][8];
      #pragma unroll
      for (int i = 0; i < 4; ++i)
        #pragma unroll
        for (int j = 0; j < 8; ++j) Y[i][j] = 0.f;

      const float* Wp = Wt + (size_t)w * RD * RD + r0;  // [k][r] layout
      #pragma unroll 4
      for (int k = 0; k < RD; ++k) {
        const float4 wv = *reinterpret_cast<const float4*>(Wp + (size_t)k * RD);
        float rb[8];
        #pragma unroll
        for (int j = 0; j < 8; ++j) rb[j] = R_T[k][b0 + j];  // wave-uniform broadcast
        #pragma unroll
        for (int j = 0; j < 8; ++j) {
          Y[0][j] += wv.x * rb[j];
          Y[1][j] += wv.y * rb[j];
          Y[2][j] += wv.z * rb[j];
          Y[3][j] += wv.w * rb[j];
        }
      }

      float lamv[4], rA, rB;
      if (w == 0) {
        rA = rho1; rB = rho2;
        #pragma unroll
        for (int i = 0; i < 4; ++i) lamv[i] = lam1[r0 + i];
      } else {
        rA = rho3; rB = rho4;
        #pragma unroll
        for (int i = 0; i < 4; ++i) lamv[i] = lam2[(size_t)(w - 1) * RD + r0 + i];
      }
      float coef[8];
      if (w == 0) {
        #pragma unroll
        for (int j = 0; j < 8; ++j) coef[j] = 1.0f;
      } else {
        #pragma unroll
        for (int j = 0; j < 8; ++j) coef[j] = dW[t][b0 + j][w - 1];
      }
      #pragma unroll
      for (int i = 0; i < 4; ++i)
        #pragma unroll
        for (int j = 0; j < 8; ++j)
          Racc[i][j] += coef[j] * fast_tanh(rA * Y[i][j] + rB * lamv[i]);
    }

    __syncthreads();  // everyone done reading R_t
    #pragma unroll
    for (int i = 0; i < 4; ++i)
      #pragma unroll
      for (int j = 0; j < 8; ++j) R_T[r0 + i][b0 + j] = Racc[i][j];
    __syncthreads();  // R_{t+1} visible
    readout(t + 1);
  }
}

extern "C" void kernel_launch(void* const* d_in, const int* in_sizes, int n_in,
                              void* d_out, int out_size, void* d_ws, size_t ws_size,
                              hipStream_t stream) {
  const float* V    = (const float*)d_in[0];
  const float* inc  = (const float*)d_in[1];
  const float* W1   = (const float*)d_in[2];
  const float* b1   = (const float*)d_in[3];
  const float* W2   = (const float*)d_in[4];
  const float* b2   = (const float*)d_in[5];
  const float* rho1 = (const float*)d_in[6];
  const float* rho2 = (const float*)d_in[7];
  const float* rho3 = (const float*)d_in[8];
  const float* rho4 = (const float*)d_in[9];
  const float* B1   = (const float*)d_in[10];
  const float* B2   = (const float*)d_in[11];
  const float* lam1 = (const float*)d_in[12];
  const float* lam2 = (const float*)d_in[13];
  const float* Wro  = (const float*)d_in[14];
  const float* bro  = (const float*)d_in[15];
  float* out = (float*)d_out;
  float* Wt = (float*)d_ws;   // 9*256*256*4 = 2.36 MB

  const int B = in_sizes[0] / 16;

  dim3 tg(8, 8, 9);
  transpose_w<<<tg, 256, 0, stream>>>(B1, B2, Wt);
  sde_main<<<B / BT, 256, 0, stream>>>(V, inc, W1, b1, W2, b2,
                                       rho1, rho2, rho3, rho4,
                                       lam1, lam2, Wro, bro, Wt, out);
}

// Round 2
// 1250.944 us; speedup vs baseline: 1.9768x; 1.9768x over previous
//
#include <hip/hip_runtime.h>

#define RD 256
#define BT 64
#define NTH 512
#define T_STEPS 9

typedef __attribute__((ext_vector_type(8))) short short8;
typedef __attribute__((ext_vector_type(4))) float f32x4;

__device__ __forceinline__ short f2bf(float f) {
  union { float f; unsigned u; } v; v.f = f;
  return (short)((v.u + 0x7FFFu + ((v.u >> 16) & 1u)) >> 16);
}
__device__ __forceinline__ float bf2f(short s) {
  union { unsigned u; float f; } v; v.u = ((unsigned)(unsigned short)s) << 16;
  return v.f;
}
__device__ __forceinline__ float fast_tanh(float x) {
  float e = __expf(2.0f * x);
  return 1.0f - 2.0f / (e + 1.0f);
}
__device__ __forceinline__ f32x4 mfma16(short8 a, short8 b, f32x4 c) {
  return __builtin_amdgcn_mfma_f32_16x16x32_bf16(a, b, c, 0, 0, 0);
}

// Pack B1 (256x256) and B2 (8x256x256) into MFMA A-fragment order, split into
// bf16 hi + lo.  Block blk = (w*16 + Mt)*8 + kk covers one 16x32 tile; lane l
// holds A[r = Mt*16 + (l&15)][k = kk*32 + (l>>4)*8 + i], i=0..7 (16B/lane).
__global__ __launch_bounds__(64) void prep_w(const float* __restrict__ B1,
                                             const float* __restrict__ B2,
                                             short* __restrict__ Whi,
                                             short* __restrict__ Wlo) {
  const int blk = blockIdx.x;
  const int w = blk >> 7, rem = blk & 127;
  const int Mt = rem >> 3, kk = rem & 7;
  const int l = threadIdx.x, c = l & 15, g = l >> 4;
  const float* src = (w == 0 ? B1 : B2 + (size_t)(w - 1) * RD * RD)
                     + (size_t)(Mt * 16 + c) * RD + kk * 32 + g * 8;
  short* dh = Whi + (size_t)blk * 512 + l * 8;
  short* dl = Wlo + (size_t)blk * 512 + l * 8;
  #pragma unroll
  for (int i = 0; i < 8; ++i) {
    float v = src[i];
    short h = f2bf(v);
    dh[i] = h;
    dl[i] = f2bf(v - bf2f(h));
  }
}

__global__ __launch_bounds__(NTH, 2) void sde_main(
    const float* __restrict__ V, const float* __restrict__ inc,
    const float* __restrict__ W1, const float* __restrict__ b1,
    const float* __restrict__ W2, const float* __restrict__ b2,
    const float* __restrict__ rho1p, const float* __restrict__ rho2p,
    const float* __restrict__ rho3p, const float* __restrict__ rho4p,
    const float* __restrict__ lam1, const float* __restrict__ lam2,
    const float* __restrict__ Wro, const float* __restrict__ bro,
    const short* __restrict__ Whi, const short* __restrict__ Wlo,
    float* __restrict__ out) {
  // B-operand (R state) fragment buffers: chunk kk (32 k) x 256 slots x 16B.
  // slot(b, gk) = b*4 + ((gk + b) & 3)  -- swizzle keeps ds_read_b128 <=2-way.
  __shared__ short8 BhiV[8 * 256];              // 32 KB
  __shared__ short8 BloV[8 * 256];              // 32 KB
  __shared__ float dW_s[T_STEPS * 8 * BT];      // 18 KB
  __shared__ float lam_s[9 * RD];               // 9 KB
  __shared__ float ro_part[8 * BT];             // 2 KB

  const int tid = threadIdx.x;
  const int wv = tid >> 6, l = tid & 63, c = l & 15, g = l >> 4;
  const int b_base = blockIdx.x * BT;
  const float rho1 = rho1p[0], rho2 = rho2p[0], rho3 = rho3p[0], rho4 = rho4p[0];

  float* W2s  = (float*)BhiV;   // prologue-only alias (32 KB exactly)
  float* actT = (float*)BloV;   // prologue-only alias (8 KB used)

  // ---- phase A: stage W2, activations, dW, lambda ----
  {
    const float4* s = (const float4*)W2;
    float4* d = (float4*)W2s;
    #pragma unroll
    for (int j = 0; j < 4; ++j) d[j * NTH + tid] = s[j * NTH + tid];
  }
  {
    const int b = tid & 63, h0 = (tid >> 6) << 2;
    const float* Vb = V + (size_t)(b_base + b) * 16;
    float v[16];
    #pragma unroll
    for (int k = 0; k < 16; ++k) v[k] = Vb[k];
    #pragma unroll
    for (int i = 0; i < 4; ++i) {
      const int h = h0 + i;
      float s = b1[h];
      #pragma unroll
      for (int k = 0; k < 16; ++k) s += v[k] * W1[h * 16 + k];
      actT[h * 64 + b] = fast_tanh(s);
    }
  }
  {
    const int b = tid >> 3, m = tid & 7;
    const float* ib = inc + (size_t)(b_base + b) * 80 + m;
    dW_s[m * BT + b] = ib[0] + ib[8];
    #pragma unroll
    for (int t = 1; t < 9; ++t) dW_s[(t * 8 + m) * BT + b] = ib[(t + 1) * 8];
  }
  for (int j = tid; j < 2304; j += NTH)
    lam_s[j] = (j < 256) ? lam1[j] : lam2[j - 256];
  __syncthreads();

  // ---- phase B: master R0 in C/D layout: rows r(mt,i)=32wv+16mt+4g+i, cols b(nt)=16nt+c
  float mast[2][4][4];
  #pragma unroll
  for (int mt = 0; mt < 2; ++mt)
    #pragma unroll
    for (int i = 0; i < 4; ++i) {
      const float bb = b2[32 * wv + 16 * mt + 4 * g + i];
      #pragma unroll
      for (int nt = 0; nt < 4; ++nt) mast[mt][nt][i] = bb;
    }
  #pragma unroll 4
  for (int h = 0; h < 32; ++h) {
    float a[4];
    #pragma unroll
    for (int nt = 0; nt < 4; ++nt) a[nt] = actT[h * 64 + nt * 16 + c];
    #pragma unroll
    for (int mt = 0; mt < 2; ++mt)
      #pragma unroll
      for (int i = 0; i < 4; ++i) {
        const float w2v = W2s[(32 * wv + 16 * mt + 4 * g + i) * 32 + h];
        #pragma unroll
        for (int nt = 0; nt < 4; ++nt) mast[mt][nt][i] += w2v * a[nt];
      }
  }

  auto partials = [&](int t) {
    float s[4] = {0.f, 0.f, 0.f, 0.f};
    #pragma unroll
    for (int mt = 0; mt < 2; ++mt)
      #pragma unroll
      for (int i = 0; i < 4; ++i) {
        const float wr = Wro[t * RD + 32 * wv + 16 * mt + 4 * g + i];
        #pragma unroll
        for (int nt = 0; nt < 4; ++nt) s[nt] += wr * mast[mt][nt][i];
      }
    #pragma unroll
    for (int nt = 0; nt < 4; ++nt) {
      s[nt] += __shfl_xor(s[nt], 16);
      s[nt] += __shfl_xor(s[nt], 32);
    }
    if (g == 0) {
      #pragma unroll
      for (int nt = 0; nt < 4; ++nt) ro_part[wv * BT + nt * 16 + c] = s[nt];
    }
  };

  // master (fp32) -> hi/lo bf16 B-fragments in LDS.  Element k(in-chunk) =
  // 16mt+4g+i -> gk = 2mt+(g>>1) (same for all i), word = 2(g&1)+(i>>1).
  auto write_bfrags = [&]() {
    #pragma unroll
    for (int mt = 0; mt < 2; ++mt) {
      const int gk = 2 * mt + (g >> 1);
      const int w0 = 2 * (g & 1);
      #pragma unroll
      for (int nt = 0; nt < 4; ++nt) {
        const int b = nt * 16 + c;
        const int slot = b * 4 + ((gk + b) & 3);
        const float x0 = mast[mt][nt][0], x1 = mast[mt][nt][1];
        const float x2 = mast[mt][nt][2], x3 = mast[mt][nt][3];
        const short a0 = f2bf(x0), a1 = f2bf(x1), a2 = f2bf(x2), a3 = f2bf(x3);
        const short c0 = f2bf(x0 - bf2f(a0)), c1 = f2bf(x1 - bf2f(a1));
        const short c2 = f2bf(x2 - bf2f(a2)), c3 = f2bf(x3 - bf2f(a3));
        unsigned* ph = (unsigned*)(BhiV + wv * 256 + slot);
        unsigned* pl = (unsigned*)(BloV + wv * 256 + slot);
        ph[w0]     = (unsigned)(unsigned short)a0 | ((unsigned)(unsigned short)a1 << 16);
        ph[w0 + 1] = (unsigned)(unsigned short)a2 | ((unsigned)(unsigned short)a3 << 16);
        pl[w0]     = (unsigned)(unsigned short)c0 | ((unsigned)(unsigned short)c1 << 16);
        pl[w0 + 1] = (unsigned)(unsigned short)c2 | ((unsigned)(unsigned short)c3 << 16);
      }
    }
  };

  partials(0);
  __syncthreads();          // W2s/actT reads done; ro_part(0) visible
  write_bfrags();
  if (tid < BT) {
    float x = bro[0];
    #pragma unroll
    for (int q = 0; q < 8; ++q) x += ro_part[q * BT + tid];
    out[(size_t)(b_base + tid) * 10] = x;
  }
  __syncthreads();          // B(0) visible

  // ---- main recurrence ----
  for (int t = 0; t < T_STEPS; ++t) {
    #pragma unroll 1
    for (int w = 0; w < 9; ++w) {
      f32x4 acc[2][4];
      const f32x4 zero = {0.f, 0.f, 0.f, 0.f};
      #pragma unroll
      for (int mt = 0; mt < 2; ++mt)
        #pragma unroll
        for (int nt = 0; nt < 4; ++nt) acc[mt][nt] = zero;

      const size_t base = ((size_t)(w * 16 + 2 * wv) * 8) * 512 + l * 8;
      const short* a0p = Whi + base;
      const short* a1p = a0p + 8 * 512;
      const short* l0p = Wlo + base;
      const short* l1p = l0p + 8 * 512;

      short8 Ah[2][2], Al[2][2];
      Ah[0][0] = *(const short8*)(a0p);
      Ah[0][1] = *(const short8*)(a1p);
      Al[0][0] = *(const short8*)(l0p);
      Al[0][1] = *(const short8*)(l1p);

      #pragma unroll
      for (int kk = 0; kk < 8; ++kk) {
        const int cur = kk & 1;
        if (kk < 7) {
          Ah[cur ^ 1][0] = *(const short8*)(a0p + (kk + 1) * 512);
          Ah[cur ^ 1][1] = *(const short8*)(a1p + (kk + 1) * 512);
          Al[cur ^ 1][0] = *(const short8*)(l0p + (kk + 1) * 512);
          Al[cur ^ 1][1] = *(const short8*)(l1p + (kk + 1) * 512);
        }
        short8 bh[4], bl[4];
        #pragma unroll
        for (int nt = 0; nt < 4; ++nt) {
          const int b = nt * 16 + c;
          const int slot = b * 4 + ((g + b) & 3);
          bh[nt] = BhiV[kk * 256 + slot];
          bl[nt] = BloV[kk * 256 + slot];
        }
        #pragma unroll
        for (int mt = 0; mt < 2; ++mt)
          #pragma unroll
          for (int nt = 0; nt < 4; ++nt)
            acc[mt][nt] = mfma16(Ah[cur][mt], bh[nt], acc[mt][nt]);
        #pragma unroll
        for (int mt = 0; mt < 2; ++mt)
          #pragma unroll
          for (int nt = 0; nt < 4; ++nt)
            acc[mt][nt] = mfma16(Ah[cur][mt], bl[nt], acc[mt][nt]);
        #pragma unroll
        for (int mt = 0; mt < 2; ++mt)
          #pragma unroll
          for (int nt = 0; nt < 4; ++nt)
            acc[mt][nt] = mfma16(Al[cur][mt], bh[nt], acc[mt][nt]);
      }

      const float rA = (w == 0) ? rho1 : rho3;
      const float rB = (w == 0) ? rho2 : rho4;
      float lamv[2][4];
      #pragma unroll
      for (int mt = 0; mt < 2; ++mt)
        #pragma unroll
        for (int i = 0; i < 4; ++i)
          lamv[mt][i] = lam_s[w * RD + 32 * wv + 16 * mt + 4 * g + i];
      float coef[4];
      if (w == 0) {
        #pragma unroll
        for (int nt = 0; nt < 4; ++nt) coef[nt] = 1.0f;
      } else {
        #pragma unroll
        for (int nt = 0; nt < 4; ++nt)
          coef[nt] = dW_s[((t * 8) + (w - 1)) * BT + nt * 16 + c];
      }
      #pragma unroll
      for (int mt = 0; mt < 2; ++mt)
        #pragma unroll
        for (int nt = 0; nt < 4; ++nt)
          #pragma unroll
          for (int i = 0; i < 4; ++i)
            mast[mt][nt][i] +=
                coef[nt] * fast_tanh(rA * acc[mt][nt][i] + rB * lamv[mt][i]);
    }

    partials(t + 1);
    __syncthreads();            // all B(t) reads done; partials visible
    if (t < 8) write_bfrags();  // B(t+1)
    if (tid < BT) {
      float x = bro[t + 1];
      #pragma unroll
      for (int q = 0; q < 8; ++q) x += ro_part[q * BT + tid];
      out[(size_t)(b_base + tid) * 10 + (t + 1)] = x;
    }
    __syncthreads();            // B(t+1) visible
  }
}

extern "C" void kernel_launch(void* const* d_in, const int* in_sizes, int n_in,
                              void* d_out, int out_size, void* d_ws, size_t ws_size,
                              hipStream_t stream) {
  const float* V    = (const float*)d_in[0];
  const float* inc  = (const float*)d_in[1];
  const float* W1   = (const float*)d_in[2];
  const float* b1   = (const float*)d_in[3];
  const float* W2   = (const float*)d_in[4];
  const float* b2   = (const float*)d_in[5];
  const float* rho1 = (const float*)d_in[6];
  const float* rho2 = (const float*)d_in[7];
  const float* rho3 = (const float*)d_in[8];
  const float* rho4 = (const float*)d_in[9];
  const float* B1   = (const float*)d_in[10];
  const float* B2   = (const float*)d_in[11];
  const float* lam1 = (const float*)d_in[12];
  const float* lam2 = (const float*)d_in[13];
  const float* Wro  = (const float*)d_in[14];
  const float* bro  = (const float*)d_in[15];
  float* out = (float*)d_out;

  short* Whi = (short*)d_ws;              // 9*16*8*512 shorts = 1.18 MB
  short* Wlo = Whi + 9 * 16 * 8 * 512;    // +1.18 MB  (total 2.36 MB)

  const int B = in_sizes[0] / 16;

  prep_w<<<9 * 16 * 8, 64, 0, stream>>>(B1, B2, Whi, Wlo);
  sde_main<<<B / BT, NTH, 0, stream>>>(V, inc, W1, b1, W2, b2,
                                       rho1, rho2, rho3, rho4,
                                       lam1, lam2, Wro, bro, Whi, Wlo, out);
}

// Round 3
// 370.436 us; speedup vs baseline: 6.6754x; 3.3770x over previous
//
#include <hip/hip_runtime.h>

#define RD 256
#define BT 64
#define NTH 512
#define T_STEPS 9

typedef __attribute__((ext_vector_type(8))) short short8;
typedef __attribute__((ext_vector_type(8))) _Float16 half8;
typedef __attribute__((ext_vector_type(4))) float f32x4;

__device__ __forceinline__ float fast_tanh(float x) {
  float e = __expf(2.0f * x);
  return 1.0f - 2.0f / (e + 1.0f);
}
__device__ __forceinline__ f32x4 mfma16h(half8 a, half8 b, f32x4 c) {
  return __builtin_amdgcn_mfma_f32_16x16x32_f16(a, b, c, 0, 0, 0);
}
__device__ __forceinline__ unsigned pack2h(float a, float b) {
  unsigned short ua = __builtin_bit_cast(unsigned short, (_Float16)a);
  unsigned short ub = __builtin_bit_cast(unsigned short, (_Float16)b);
  return (unsigned)ua | ((unsigned)ub << 16);
}

// Pack B1 (256x256) and B2 (8x256x256) into fp16 MFMA A-fragment order.
// Block blk = (w*16 + Mt)*8 + kk covers one 16x32 tile; lane l holds
// A[r = Mt*16 + (l&15)][k = kk*32 + (l>>4)*8 + i], i=0..7 (16B/lane).
__global__ __launch_bounds__(64) void prep_w(const float* __restrict__ B1,
                                             const float* __restrict__ B2,
                                             _Float16* __restrict__ Wh) {
  const int blk = blockIdx.x;
  const int w = blk >> 7, rem = blk & 127;
  const int Mt = rem >> 3, kk = rem & 7;
  const int l = threadIdx.x, c = l & 15, g = l >> 4;
  const float* src = (w == 0 ? B1 : B2 + (size_t)(w - 1) * RD * RD)
                     + (size_t)(Mt * 16 + c) * RD + kk * 32 + g * 8;
  _Float16* d = Wh + (size_t)blk * 512 + l * 8;
  #pragma unroll
  for (int i = 0; i < 8; ++i) d[i] = (_Float16)src[i];
}

__global__ __launch_bounds__(NTH, 2) void sde_main(
    const float* __restrict__ V, const float* __restrict__ inc,
    const float* __restrict__ W1, const float* __restrict__ b1,
    const float* __restrict__ W2, const float* __restrict__ b2,
    const float* __restrict__ rho1p, const float* __restrict__ rho2p,
    const float* __restrict__ rho3p, const float* __restrict__ rho4p,
    const float* __restrict__ lam1, const float* __restrict__ lam2,
    const float* __restrict__ Wro, const float* __restrict__ bro,
    const _Float16* __restrict__ Wh, float* __restrict__ out) {
  // Exchange buffer: R_t as fp16 B-fragments, slot (kk, gq, b):
  //   element i at ((kk*4+gq)*64 + b)*8 + i  holds R[k=kk*32+gq*8+i][b].
  __shared__ short8 Bex[2048];                  // 32 KB (aliases W2s in prologue)
  __shared__ float dW_s[T_STEPS * 8 * BT];      // 18 KB
  __shared__ float lam_s[9 * RD];               // 9 KB (aliases actT in prologue)
  __shared__ float ro_part[8 * BT];             // 2 KB

  const int tid = threadIdx.x;
  const int wv = tid >> 6, l = tid & 63, c = l & 15, g = l >> 4;
  const int b_base = blockIdx.x * BT;
  const float rho1 = rho1p[0], rho2 = rho2p[0], rho3 = rho3p[0], rho4 = rho4p[0];

  float* W2s  = (float*)Bex;   // 32 KB, prologue only
  float* actT = lam_s;         // 8 KB of 9 KB region, prologue only

  // ---- phase A: stage W2, activations, dW ----
  {
    const float4* s = (const float4*)W2;
    float4* d = (float4*)W2s;
    #pragma unroll
    for (int j = 0; j < 4; ++j) d[j * NTH + tid] = s[j * NTH + tid];
  }
  {
    const int b = tid & 63, h0 = (tid >> 6) << 2;
    const float* Vb = V + (size_t)(b_base + b) * 16;
    float v[16];
    #pragma unroll
    for (int k = 0; k < 16; ++k) v[k] = Vb[k];
    #pragma unroll
    for (int i = 0; i < 4; ++i) {
      const int h = h0 + i;
      float s = b1[h];
      #pragma unroll
      for (int k = 0; k < 16; ++k) s += v[k] * W1[h * 16 + k];
      actT[h * 64 + b] = fast_tanh(s);
    }
  }
  {
    const int b = tid >> 3, m = tid & 7;
    const float* ib = inc + (size_t)(b_base + b) * 80 + m;
    dW_s[m * BT + b] = ib[0] + ib[8];
    #pragma unroll
    for (int t = 1; t < 9; ++t) dW_s[(t * 8 + m) * BT + b] = ib[(t + 1) * 8];
  }
  __syncthreads();

  // ---- phase B: R0 in C/D layout: rows 32wv+16mt+4g+i, cols 16nt+c ----
  float mast[2][4][4];
  #pragma unroll
  for (int mt = 0; mt < 2; ++mt)
    #pragma unroll
    for (int i = 0; i < 4; ++i) {
      const float bb = b2[32 * wv + 16 * mt + 4 * g + i];
      #pragma unroll
      for (int nt = 0; nt < 4; ++nt) mast[mt][nt][i] = bb;
    }
  #pragma unroll 4
  for (int h = 0; h < 32; ++h) {
    float a[4];
    #pragma unroll
    for (int nt = 0; nt < 4; ++nt) a[nt] = actT[h * 64 + nt * 16 + c];
    #pragma unroll
    for (int mt = 0; mt < 2; ++mt)
      #pragma unroll
      for (int i = 0; i < 4; ++i) {
        const float w2v = W2s[(32 * wv + 16 * mt + 4 * g + i) * 32 + h];
        #pragma unroll
        for (int nt = 0; nt < 4; ++nt) mast[mt][nt][i] += w2v * a[nt];
      }
  }

  auto partials = [&](int t) {
    float s[4] = {0.f, 0.f, 0.f, 0.f};
    #pragma unroll
    for (int mt = 0; mt < 2; ++mt)
      #pragma unroll
      for (int i = 0; i < 4; ++i) {
        const float wr = Wro[t * RD + 32 * wv + 16 * mt + 4 * g + i];
        #pragma unroll
        for (int nt = 0; nt < 4; ++nt) s[nt] += wr * mast[mt][nt][i];
      }
    #pragma unroll
    for (int nt = 0; nt < 4; ++nt) {
      s[nt] += __shfl_xor(s[nt], 16);
      s[nt] += __shfl_xor(s[nt], 32);
    }
    if (g == 0) {
      #pragma unroll
      for (int nt = 0; nt < 4; ++nt) ro_part[wv * BT + nt * 16 + c] = s[nt];
    }
  };

  // master fp32 -> fp16 exchange fragments
  auto write_ex = [&]() {
    #pragma unroll
    for (int mt = 0; mt < 2; ++mt) {
      const int gq = 2 * mt + (g >> 1);
      const int half8B = g & 1;  // which 8B half of the 16B slot
      #pragma unroll
      for (int nt = 0; nt < 4; ++nt) {
        const int slot = (wv * 4 + gq) * 64 + nt * 16 + c;
        uint2 pk;
        pk.x = pack2h(mast[mt][nt][0], mast[mt][nt][1]);
        pk.y = pack2h(mast[mt][nt][2], mast[mt][nt][3]);
        *((uint2*)((char*)&Bex[slot] + half8B * 8)) = pk;
      }
    }
  };

  partials(0);
  __syncthreads();   // phase-B reads of W2s/actT done; ro_part(0) visible
  for (int j = tid; j < 2304; j += NTH)
    lam_s[j] = (j < 256) ? lam1[j] : lam2[j - 256];
  if (tid < BT) {
    float x = bro[0];
    #pragma unroll
    for (int q = 0; q < 8; ++q) x += ro_part[q * BT + tid];
    out[(size_t)(b_base + tid) * 10] = x;
  }
  write_ex();
  __syncthreads();   // lam + exchange(R0) visible

  const int wavebase = 2 * wv * 4096 + l * 8;

  for (int t = 0; t < T_STEPS; ++t) {
    // B-fragments for the whole t-step into registers (reused across all 9 w)
    half8 Breg[8][4];
    #pragma unroll
    for (int kk = 0; kk < 8; ++kk)
      #pragma unroll
      for (int nt = 0; nt < 4; ++nt)
        Breg[kk][nt] = __builtin_bit_cast(
            half8, Bex[(kk * 4 + (l >> 4)) * 64 + nt * 16 + (l & 15)]);

    // rolling 2-deep A prefetch over the flattened 72-chunk stream
    half8 Abuf[2][2];
    #pragma unroll
    for (int mt = 0; mt < 2; ++mt) {
      Abuf[0][mt] = *(const half8*)(Wh + (size_t)(0 * 65536 + mt * 4096 + 0 * 512) + wavebase);
      Abuf[1][mt] = *(const half8*)(Wh + (size_t)(0 * 65536 + mt * 4096 + 1 * 512) + wavebase);
    }

    #pragma unroll 1
    for (int w = 0; w < 9; ++w) {
      f32x4 acc[2][4];
      const f32x4 zero = {0.f, 0.f, 0.f, 0.f};
      #pragma unroll
      for (int mt = 0; mt < 2; ++mt)
        #pragma unroll
        for (int nt = 0; nt < 4; ++nt) acc[mt][nt] = zero;

      #pragma unroll
      for (int kk = 0; kk < 8; ++kk) {
        const int s = w * 8 + kk, cur = s & 1;
        #pragma unroll
        for (int mt = 0; mt < 2; ++mt)
          #pragma unroll
          for (int nt = 0; nt < 4; ++nt)
            acc[mt][nt] = mfma16h(Abuf[cur][mt], Breg[kk][nt], acc[mt][nt]);
        if (s + 2 < 72) {
          const int s2 = s + 2;
          #pragma unroll
          for (int mt = 0; mt < 2; ++mt)
            Abuf[cur][mt] = *(const half8*)(
                Wh + (size_t)((s2 >> 3) * 65536 + mt * 4096 + (s2 & 7) * 512) + wavebase);
        }
      }

      const float rA = (w == 0) ? rho1 : rho3;
      const float rB = (w == 0) ? rho2 : rho4;
      float rlam[2][4];
      #pragma unroll
      for (int mt = 0; mt < 2; ++mt)
        #pragma unroll
        for (int i = 0; i < 4; ++i)
          rlam[mt][i] = rB * lam_s[w * RD + 32 * wv + 16 * mt + 4 * g + i];
      float coef[4];
      if (w == 0) {
        #pragma unroll
        for (int nt = 0; nt < 4; ++nt) coef[nt] = 1.0f;
      } else {
        #pragma unroll
        for (int nt = 0; nt < 4; ++nt)
          coef[nt] = dW_s[((t * 8) + (w - 1)) * BT + nt * 16 + c];
      }
      #pragma unroll
      for (int mt = 0; mt < 2; ++mt)
        #pragma unroll
        for (int nt = 0; nt < 4; ++nt)
          #pragma unroll
          for (int i = 0; i < 4; ++i)
            mast[mt][nt][i] +=
                coef[nt] * fast_tanh(rA * acc[mt][nt][i] + rlam[mt][i]);
    }

    partials(t + 1);
    __syncthreads();   // all Breg reads + ro_part writes complete
    if (tid < BT) {
      float x = bro[t + 1];
      #pragma unroll
      for (int q = 0; q < 8; ++q) x += ro_part[q * BT + tid];
      out[(size_t)(b_base + tid) * 10 + (t + 1)] = x;
    }
    if (t < T_STEPS - 1) write_ex();
    __syncthreads();   // exchange(R_{t+1}) visible
  }
}

extern "C" void kernel_launch(void* const* d_in, const int* in_sizes, int n_in,
                              void* d_out, int out_size, void* d_ws, size_t ws_size,
                              hipStream_t stream) {
  const float* V    = (const float*)d_in[0];
  const float* inc  = (const float*)d_in[1];
  const float* W1   = (const float*)d_in[2];
  const float* b1   = (const float*)d_in[3];
  const float* W2   = (const float*)d_in[4];
  const float* b2   = (const float*)d_in[5];
  const float* rho1 = (const float*)d_in[6];
  const float* rho2 = (const float*)d_in[7];
  const float* rho3 = (const float*)d_in[8];
  const float* rho4 = (const float*)d_in[9];
  const float* B1   = (const float*)d_in[10];
  const float* B2   = (const float*)d_in[11];
  const float* lam1 = (const float*)d_in[12];
  const float* lam2 = (const float*)d_in[13];
  const float* Wro  = (const float*)d_in[14];
  const float* bro  = (const float*)d_in[15];
  float* out = (float*)d_out;

  _Float16* Wh = (_Float16*)d_ws;   // 9*16*8*512 halves = 1.18 MB

  const int B = in_sizes[0] / 16;

  prep_w<<<9 * 16 * 8, 64, 0, stream>>>(B1, B2, Wh);
  sde_main<<<B / BT, NTH, 0, stream>>>(V, inc, W1, b1, W2, b2,
                                       rho1, rho2, rho3, rho4,
                                       lam1, lam2, Wro, bro, Wh, out);
}